// Round 1
// baseline (537.021 us; speedup 1.0000x reference)
//
#include <hip/hip_runtime.h>
#include <stdint.h>

#define NEG_SLOPE 0.01f
#define CHUNK 4096

typedef float f32x4 __attribute__((ext_vector_type(4)));
typedef short short8 __attribute__((ext_vector_type(8)));

__device__ inline short f2bf(float f) {
    union { float f; uint32_t u; } x; x.f = f;
    uint32_t r = x.u + 0x7FFF + ((x.u >> 16) & 1);   // RNE
    return (short)(r >> 16);
}

// ---------------- K0: init ----------------
__global__ void k0_init(int* head_cnt, int* head_cur, int* type_cnt,
                        int* perm_type, int N, int PT) {
    int i = blockIdx.x * blockDim.x + threadIdx.x;
    if (i < N) { head_cnt[i] = 0; head_cur[i] = 0; }
    if (i < 16) type_cnt[i] = 0;
    if (i < PT) perm_type[i] = -1;
}

// ---------------- K1: histograms (type via wave-ballot + LDS, head direct) ----
__global__ void __launch_bounds__(256) k1_hist(
        const int* __restrict__ head, const int* __restrict__ etype, int E,
        int* head_cnt, int* type_cnt) {
    __shared__ int lcnt[16];
    int t = threadIdx.x, lane = t & 63;
    if (t < 16) lcnt[t] = 0;
    __syncthreads();
    long long base = (long long)blockIdx.x * CHUNK;
    for (int i = t; i < CHUNK; i += blockDim.x) {
        long long e = base + i;
        bool valid = e < E;
        int ty = -1;
        if (valid) {
            ty = etype[e];
            atomicAdd(&head_cnt[head[e]], 1);
        }
        for (int r = 0; r < 16; ++r) {
            unsigned long long m = __ballot(valid && ty == r);
            if (m && lane == __ffsll(m) - 1)
                atomicAdd(&lcnt[r], (int)__popcll(m));
        }
    }
    __syncthreads();
    if (t < 16 && lcnt[t]) atomicAdd(&type_cnt[t], lcnt[t]);
}

// ---------------- K2a: per-block partial sums of head_cnt ----------------
__global__ void __launch_bounds__(512) k2a(const int* __restrict__ head_cnt,
                                           int N, int* partial) {
    __shared__ int sw[8];
    int i = blockIdx.x * 512 + threadIdx.x;
    int v = (i < N) ? head_cnt[i] : 0;
    for (int off = 32; off; off >>= 1) v += __shfl_down(v, off);
    int w = threadIdx.x >> 6, lane = threadIdx.x & 63;
    if (lane == 0) sw[w] = v;
    __syncthreads();
    if (threadIdx.x == 0) {
        int s = 0;
        for (int j = 0; j < 8; ++j) s += sw[j];
        partial[blockIdx.x] = s;
    }
}

// ---------------- K2b: serial scans (small) ----------------
__global__ void k2b(const int* partial, int nb, int* blk_off,
                    const int* type_cnt, int* type_off_pad, int* type_fill) {
    if (blockIdx.x == 0 && threadIdx.x == 0) {
        int run = 0;
        for (int b = 0; b < nb; ++b) { blk_off[b] = run; run += partial[b]; }
        int r2 = 0;
        for (int r = 0; r < 16; ++r) {
            type_off_pad[r] = r2;
            type_fill[r] = r2;
            r2 += (type_cnt[r] + 15) & ~15;   // pad buckets to 16
        }
        type_off_pad[16] = r2;
    }
}

// ---------------- K2c: block-local exclusive scan -> head_off ----------------
__global__ void __launch_bounds__(512) k2c(const int* __restrict__ head_cnt,
                                           int N, const int* __restrict__ blk_off,
                                           int* head_off, int E) {
    __shared__ int s[512];
    int t = threadIdx.x;
    int i = blockIdx.x * 512 + t;
    int v = (i < N) ? head_cnt[i] : 0;
    s[t] = v;
    __syncthreads();
    for (int off = 1; off < 512; off <<= 1) {
        int x = (t >= off) ? s[t - off] : 0;
        __syncthreads();
        s[t] += x;
        __syncthreads();
    }
    if (i < N) head_off[i] = s[t] - v + blk_off[blockIdx.x];
    if (i == 0) head_off[N] = E;
}

// ---------------- K3: scatter into type buckets + head CSR ----------------
__global__ void __launch_bounds__(256) k3_scatter(
        const int* __restrict__ head, const int* __restrict__ etype, int E,
        const int* __restrict__ head_off, int* head_cur,
        int* type_fill, int* perm_type, int* perm_head) {
    __shared__ int lcnt[16], lbase[16], lcur[16];
    int t = threadIdx.x, lane = t & 63;
    if (t < 16) { lcnt[t] = 0; lcur[t] = 0; }
    __syncthreads();
    long long base = (long long)blockIdx.x * CHUNK;
    // phase A: block-local type counts
    for (int i = t; i < CHUNK; i += blockDim.x) {
        long long e = base + i;
        bool valid = e < E;
        int ty = valid ? etype[e] : -1;
        for (int r = 0; r < 16; ++r) {
            unsigned long long m = __ballot(valid && ty == r);
            if (m && lane == __ffsll(m) - 1)
                atomicAdd(&lcnt[r], (int)__popcll(m));
        }
    }
    __syncthreads();
    // phase B: one global atomic per (block, type)
    if (t < 16) lbase[t] = atomicAdd(&type_fill[t], lcnt[t]);
    __syncthreads();
    // phase C: emit positions
    for (int i = t; i < CHUNK; i += blockDim.x) {
        long long e = base + i;
        bool valid = e < E;
        int ty = valid ? etype[e] : -1;
        for (int r = 0; r < 16; ++r) {
            bool mine = valid && (ty == r);
            unsigned long long m = __ballot(mine);
            if (!m) continue;
            int leader = __ffsll(m) - 1;
            if (mine) {
                int wb = 0;
                if (lane == leader) wb = atomicAdd(&lcur[r], (int)__popcll(m));
                wb = __shfl(wb, leader);
                int rank = (int)__popcll(m & ((1ull << lane) - 1ull));
                perm_type[lbase[r] + wb + rank] = (int)e;
            }
        }
        if (valid) {
            int h = head[e];
            int p2 = head_off[h] + atomicAdd(&head_cur[h], 1);
            perm_head[p2] = (int)e;
        }
    }
}

// ---------------- K3b: per-group relation id ----------------
__global__ void k3b(const int* __restrict__ type_off_pad, int* group_rel, int Gmax) {
    int g = blockIdx.x * blockDim.x + threadIdx.x;
    if (g >= Gmax) return;
    int total = type_off_pad[16] >> 4;
    if (g >= total) return;
    int s = g << 4;
    int r = 0;
    while (r < 15 && s >= type_off_pad[r + 1]) ++r;
    group_rel[g] = r;
}

// ---------------- K4: scores via MFMA (16 edges/group/wave) ----------------
__global__ void __launch_bounds__(256) k4_scores(
        const float* __restrict__ ego, const float* __restrict__ rw,
        const int* __restrict__ head, const int* __restrict__ tail,
        const int* __restrict__ perm_type, const int* __restrict__ group_rel,
        const int* __restrict__ type_off_pad, float* __restrict__ exp_s,
        int n_waves) {
    int wave = (blockIdx.x * blockDim.x + threadIdx.x) >> 6;
    int lane = threadIdx.x & 63;
    int c = lane & 15, q = lane >> 4;
    int G = type_off_pad[16] >> 4;
    int per = (G + n_waves - 1) / n_waves;
    int g0 = wave * per;
    int g1 = min(G, g0 + per);
    int cur_r = -1;
    short8 bf[4][2];   // B frags: [n-tile][k-half], B[k][n] = W[k][n]
    for (int g = g0; g < g1; ++g) {
        int r = group_rel[g];
        if (r != cur_r) {
            cur_r = r;
            const float* W = rw + r * 4096;
            for (int t4 = 0; t4 < 4; ++t4)
                for (int kb = 0; kb < 2; ++kb) {
                    short8 f;
                    for (int j = 0; j < 8; ++j) {
                        int k = kb * 32 + q * 8 + j;
                        f[j] = f2bf(W[k * 64 + t4 * 16 + c]);
                    }
                    bf[t4][kb] = f;
                }
        }
        // A frags: row m = c (lane&15) = edge-in-group; k = kb*32 + q*8 + j
        int e_m = perm_type[(g << 4) + c];
        bool valid = e_m >= 0;
        int hn = valid ? head[e_m] : 0;
        short8 a0, a1;
        if (valid) {
            const float* hr = ego + (long long)hn * 64 + q * 8;
            float4 v0 = *(const float4*)(hr);
            float4 v1 = *(const float4*)(hr + 4);
            float4 v2 = *(const float4*)(hr + 32);
            float4 v3 = *(const float4*)(hr + 36);
            a0[0] = f2bf(v0.x); a0[1] = f2bf(v0.y); a0[2] = f2bf(v0.z); a0[3] = f2bf(v0.w);
            a0[4] = f2bf(v1.x); a0[5] = f2bf(v1.y); a0[6] = f2bf(v1.z); a0[7] = f2bf(v1.w);
            a1[0] = f2bf(v2.x); a1[1] = f2bf(v2.y); a1[2] = f2bf(v2.z); a1[3] = f2bf(v2.w);
            a1[4] = f2bf(v3.x); a1[5] = f2bf(v3.y); a1[6] = f2bf(v3.z); a1[7] = f2bf(v3.w);
        } else {
            for (int j = 0; j < 8; ++j) { a0[j] = 0; a1[j] = 0; }
        }
        f32x4 acc[4];
        for (int t4 = 0; t4 < 4; ++t4) {
            f32x4 z = {0.f, 0.f, 0.f, 0.f};
            z = __builtin_amdgcn_mfma_f32_16x16x32_bf16(a0, bf[t4][0], z, 0, 0, 0);
            z = __builtin_amdgcn_mfma_f32_16x16x32_bf16(a1, bf[t4][1], z, 0, 0, 0);
            acc[t4] = z;
        }
        // fp32 dot with tail rows: C/D layout row = q*4+i, col = t4*16+c
        float p[4];
        for (int i = 0; i < 4; ++i) {
            int ei = __shfl(e_m, q * 4 + i);
            int tn = (ei >= 0) ? tail[ei] : 0;
            const float* tr = ego + (long long)tn * 64 + c;
            float s = acc[0][i] * tr[0];
            s += acc[1][i] * tr[16];
            s += acc[2][i] * tr[32];
            s += acc[3][i] * tr[48];
            p[i] = s;
        }
        // reduce over the 16 lanes sharing q (xor<16 keeps q fixed)
        for (int off = 1; off < 16; off <<= 1) {
            p[0] += __shfl_xor(p[0], off);
            p[1] += __shfl_xor(p[1], off);
            p[2] += __shfl_xor(p[2], off);
            p[3] += __shfl_xor(p[3], off);
        }
        int m2 = q * 4 + (c & 3);
        int e_sel = __shfl(e_m, m2);                    // before divergence
        float sv = (c & 3) == 0 ? p[0] : (c & 3) == 1 ? p[1] : (c & 3) == 2 ? p[2] : p[3];
        if (c < 4 && e_sel >= 0) {
            float s = sv > 0.f ? sv : NEG_SLOPE * sv;   // leaky_relu
            exp_s[e_sel] = expf(s);
        }
    }
}

// ---------------- K5: per-head aggregation (one wave per node) ----------------
__global__ void __launch_bounds__(256) k5_agg(
        const float* __restrict__ ego, const int* __restrict__ tail,
        const int* __restrict__ perm_head, const int* __restrict__ head_off,
        const float* __restrict__ exp_s, float* __restrict__ out, int N) {
    int wave = (blockIdx.x * blockDim.x + threadIdx.x) >> 6;
    int lane = threadIdx.x & 63;
    if (wave >= N) return;
    int s0 = head_off[wave], s1 = head_off[wave + 1];
    int cnt = s1 - s0;
    float acc = 0.f, dsum = 0.f;
    for (int b = s0; b < s1; b += 64) {
        int idx = b + lane;
        int tn = 0; float x = 0.f;
        if (idx < s1) {
            int e = perm_head[idx];
            tn = tail[e];
            x = exp_s[e];
        }
        int mcnt = min(64, s1 - b);
        for (int j = 0; j < mcnt; ++j) {
            int tj = __shfl(tn, j);
            float xj = __shfl(x, j);
            acc += xj * ego[(long long)tj * 64 + lane];
            dsum += xj;
        }
    }
    float o = (cnt > 0) ? acc / (dsum * (float)cnt) : 0.f;
    out[(long long)wave * 64 + lane] = o;
}

extern "C" void kernel_launch(void* const* d_in, const int* in_sizes, int n_in,
                              void* d_out, int out_size, void* d_ws, size_t ws_size,
                              hipStream_t stream) {
    const float* ego = (const float*)d_in[0];
    const float* rw  = (const float*)d_in[1];
    const int* eidx  = (const int*)d_in[2];
    const int* etyp  = (const int*)d_in[3];
    int N = in_sizes[0] / 64;
    int E = in_sizes[3];
    const int* head = eidx;
    const int* tail = eidx + E;
    float* out = (float*)d_out;

    // workspace layout (256B aligned sections), ~17 MB total
    char* ws = (char*)d_ws;
    size_t o = 0;
    auto take = [&](size_t bytes) -> char* {
        char* p = ws + o;
        o = (o + bytes + 255) & ~(size_t)255;
        return p;
    };
    int PT   = E + 256;                 // perm_type with per-bucket pad (<=15 x 16)
    int Gmax = (E + 15) / 16 + 16;
    int nb2  = (N + 511) / 512;
    float* exp_s      = (float*)take((size_t)E * 4);
    int* perm_type    = (int*)take((size_t)PT * 4);
    int* perm_head    = (int*)take((size_t)E * 4);
    int* head_cnt     = (int*)take((size_t)N * 4);
    int* head_off     = (int*)take((size_t)(N + 1) * 4);
    int* head_cur     = (int*)take((size_t)N * 4);
    int* type_cnt     = (int*)take(64);
    int* type_off_pad = (int*)take(68);
    int* type_fill    = (int*)take(64);
    int* group_rel    = (int*)take((size_t)Gmax * 4);
    int* partial      = (int*)take((size_t)nb2 * 4);
    int* blk_off      = (int*)take((size_t)nb2 * 4);
    (void)ws_size; (void)n_in; (void)out_size;

    int initN = (N > PT ? N : PT);
    k0_init<<<(initN + 255) / 256, 256, 0, stream>>>(head_cnt, head_cur, type_cnt, perm_type, N, PT);

    int nchunks = (E + CHUNK - 1) / CHUNK;
    k1_hist<<<nchunks, 256, 0, stream>>>(head, etyp, E, head_cnt, type_cnt);

    k2a<<<nb2, 512, 0, stream>>>(head_cnt, N, partial);
    k2b<<<1, 64, 0, stream>>>(partial, nb2, blk_off, type_cnt, type_off_pad, type_fill);
    k2c<<<nb2, 512, 0, stream>>>(head_cnt, N, blk_off, head_off, E);

    k3_scatter<<<nchunks, 256, 0, stream>>>(head, etyp, E, head_off, head_cur,
                                            type_fill, perm_type, perm_head);
    k3b<<<(Gmax + 255) / 256, 256, 0, stream>>>(type_off_pad, group_rel, Gmax);

    int blocks4 = 1024;                   // 4096 waves, ~20 groups each
    int n_waves = blocks4 * (256 / 64);
    k4_scores<<<blocks4, 256, 0, stream>>>(ego, rw, head, tail, perm_type, group_rel,
                                           type_off_pad, exp_s, n_waves);

    k5_agg<<<(N + 3) / 4, 256, 0, stream>>>(ego, tail, perm_head, head_off, exp_s, out, N);
}

// Round 2
// 362.175 us; speedup vs baseline: 1.4828x; 1.4828x over previous
//
#include <hip/hip_runtime.h>
#include <stdint.h>

#define NEG_SLOPE 0.01f
#define CHUNK 4096

typedef float f32x4 __attribute__((ext_vector_type(4)));
typedef short short8 __attribute__((ext_vector_type(8)));

__device__ inline short f2bf(float f) {
    union { float f; uint32_t u; } x; x.f = f;
    uint32_t r = x.u + 0x7FFF + ((x.u >> 16) & 1);   // RNE
    return (short)(r >> 16);
}
__device__ inline float bf2f(unsigned short u) {
    union { uint32_t u; float f; } x; x.u = ((uint32_t)u) << 16; return x.f;
}

// ---------------- K0: init ----------------
__global__ void k0_init(int* head_cnt, int* head_cur, int* type_cnt,
                        int* perm_type, int N, int PT) {
    int i = blockIdx.x * blockDim.x + threadIdx.x;
    if (i < N) { head_cnt[i] = 0; head_cur[i] = 0; }
    if (i < 16) type_cnt[i] = 0;
    if (i < PT) perm_type[i] = -1;
}

// ---------------- K_bf: ego fp32 -> bf16 table ----------------
__global__ void __launch_bounds__(256) k_bf(const float* __restrict__ ego,
                                            unsigned short* __restrict__ ego_bf,
                                            int NE8) {
    int i = blockIdx.x * 256 + threadIdx.x;
    if (i >= NE8) return;
    const float4* p = (const float4*)ego + (size_t)i * 2;
    float4 a = p[0], b = p[1];
    short8 v;
    v[0] = f2bf(a.x); v[1] = f2bf(a.y); v[2] = f2bf(a.z); v[3] = f2bf(a.w);
    v[4] = f2bf(b.x); v[5] = f2bf(b.y); v[6] = f2bf(b.z); v[7] = f2bf(b.w);
    *(short8*)(ego_bf + (size_t)i * 8) = v;
}

// ---------------- K_w: pack W^T as MFMA A-fragments (bf16) ----------------
// frag layout: wfrag[((r*4 + t4)*2 + kh)*512 + lane*8 + j]
// A[m = t4*16 + (lane&15)][k = kh*32 + (lane>>4)*8 + j] = W[r][k][m]
__global__ void __launch_bounds__(512) k_w(const float* __restrict__ rw,
                                           short* __restrict__ wfrag) {
    int r = blockIdx.x;
    int tid = threadIdx.x;
    int lane = tid & 63, pair = tid >> 6;
    int t4 = pair >> 1, kh = pair & 1;
    int c = lane & 15, q = lane >> 4;
    int m = t4 * 16 + c;
    short8 f;
    for (int j = 0; j < 8; ++j) {
        int k = kh * 32 + q * 8 + j;
        f[j] = f2bf(rw[r * 4096 + k * 64 + m]);
    }
    *(short8*)(wfrag + ((size_t)((r * 4 + t4) * 2 + kh) * 64 + lane) * 8) = f;
}

// ---------------- K1: histograms (LDS atomics for type, direct for head) ----
__global__ void __launch_bounds__(256) k1_hist(
        const int* __restrict__ head, const int* __restrict__ etype, int E,
        int* head_cnt, int* type_cnt) {
    __shared__ int lcnt[16];
    int t = threadIdx.x;
    if (t < 16) lcnt[t] = 0;
    __syncthreads();
    long long base = (long long)blockIdx.x * CHUNK;
    for (int i = t; i < CHUNK; i += 256) {
        long long e = base + i;
        if (e < E) {
            atomicAdd(&head_cnt[head[e]], 1);
            atomicAdd(&lcnt[etype[e]], 1);
        }
    }
    __syncthreads();
    if (t < 16 && lcnt[t]) atomicAdd(&type_cnt[t], lcnt[t]);
}

// ---------------- K2a: per-block partial sums of head_cnt ----------------
__global__ void __launch_bounds__(512) k2a(const int* __restrict__ head_cnt,
                                           int N, int* partial) {
    __shared__ int sw[8];
    int i = blockIdx.x * 512 + threadIdx.x;
    int v = (i < N) ? head_cnt[i] : 0;
    for (int off = 32; off; off >>= 1) v += __shfl_down(v, off);
    int w = threadIdx.x >> 6, lane = threadIdx.x & 63;
    if (lane == 0) sw[w] = v;
    __syncthreads();
    if (threadIdx.x == 0) {
        int s = 0;
        for (int j = 0; j < 8; ++j) s += sw[j];
        partial[blockIdx.x] = s;
    }
}

// ---------------- K2b: wave-parallel scans ----------------
__global__ void k2b(const int* __restrict__ partial, int nb, int* blk_off,
                    const int* __restrict__ type_cnt, int* type_off_pad,
                    int* type_fill) {
    int lane = threadIdx.x;   // 64 threads = 1 wave
    int run = 0;
    for (int chunk = 0; chunk < nb; chunk += 64) {
        int i = chunk + lane;
        int orig = (i < nb) ? partial[i] : 0;
        int v = orig;
        for (int off = 1; off < 64; off <<= 1) {
            int u = __shfl_up(v, off);
            if (lane >= off) v += u;
        }
        if (i < nb) blk_off[i] = run + v - orig;
        run += __shfl(v, 63);
    }
    int tv = (lane < 16) ? type_cnt[lane] : 0;
    int tp = (tv + 15) & ~15;                 // pad buckets to 16
    int inc = tp;
    for (int off = 1; off < 16; off <<= 1) {
        int u = __shfl_up(inc, off);
        if (lane >= off) inc += u;
    }
    if (lane < 16) {
        int excl = inc - tp;
        type_off_pad[lane] = excl;
        type_fill[lane] = excl;
        if (lane == 15) type_off_pad[16] = inc;
    }
}

// ---------------- K2c: block-local exclusive scan -> head_off ----------------
__global__ void __launch_bounds__(512) k2c(const int* __restrict__ head_cnt,
                                           int N, const int* __restrict__ blk_off,
                                           int* head_off, int E) {
    __shared__ int s[512];
    int t = threadIdx.x;
    int i = blockIdx.x * 512 + t;
    int v = (i < N) ? head_cnt[i] : 0;
    s[t] = v;
    __syncthreads();
    for (int off = 1; off < 512; off <<= 1) {
        int x = (t >= off) ? s[t - off] : 0;
        __syncthreads();
        s[t] += x;
        __syncthreads();
    }
    if (i < N) head_off[i] = s[t] - v + blk_off[blockIdx.x];
    if (i == 0) head_off[N] = E;
}

// ---------------- K3: scatter into type buckets + head CSR (LDS atomics) ----
__global__ void __launch_bounds__(256) k3_scatter(
        const int* __restrict__ head, const int* __restrict__ etype, int E,
        const int* __restrict__ head_off, int* head_cur,
        int* type_fill, int* perm_type, int* perm_head) {
    __shared__ int lcnt[16], lbase[16], lcur[16];
    int t = threadIdx.x;
    if (t < 16) { lcnt[t] = 0; lcur[t] = 0; }
    __syncthreads();
    long long base = (long long)blockIdx.x * CHUNK;
    for (int i = t; i < CHUNK; i += 256) {
        long long e = base + i;
        if (e < E) atomicAdd(&lcnt[etype[e]], 1);
    }
    __syncthreads();
    if (t < 16) lbase[t] = atomicAdd(&type_fill[t], lcnt[t]);
    __syncthreads();
    for (int i = t; i < CHUNK; i += 256) {
        long long e = base + i;
        if (e < E) {
            int ty = etype[e];
            int rk = atomicAdd(&lcur[ty], 1);
            perm_type[lbase[ty] + rk] = (int)e;
            int h = head[e];
            int p2 = head_off[h] + atomicAdd(&head_cur[h], 1);
            perm_head[p2] = (int)e;
        }
    }
}

// ---------------- K3b: per-group relation id ----------------
__global__ void k3b(const int* __restrict__ type_off_pad, int* group_rel, int Gmax) {
    int g = blockIdx.x * blockDim.x + threadIdx.x;
    if (g >= Gmax) return;
    int total = type_off_pad[16] >> 4;
    if (g >= total) return;
    int s = g << 4;
    int r = 0;
    while (r < 15 && s >= type_off_pad[r + 1]) ++r;
    group_rel[g] = r;
}

// ---------------- K4: scores via MFMA, swapped operands ----------------
// D = W^T(frag A) x HeadRows(frag B): D col (lane&15) = edge slot,
// D row (q*4+i, tiled by t4) = output column. Tail dot is 4 ushort4 loads
// + 16 in-lane FMAs + 2 shfl_xor.
__global__ void __launch_bounds__(256) k4_scores(
        const unsigned short* __restrict__ ego_bf, const short* __restrict__ wfrag,
        const int* __restrict__ head, const int* __restrict__ tail,
        const int* __restrict__ perm_type, const int* __restrict__ group_rel,
        const int* __restrict__ type_off_pad, float* __restrict__ exp_s,
        int n_waves) {
    int wave = (blockIdx.x * blockDim.x + threadIdx.x) >> 6;
    int lane = threadIdx.x & 63;
    int c = lane & 15, q = lane >> 4;
    int G = type_off_pad[16] >> 4;
    int per = (G + n_waves - 1) / n_waves;
    int g0 = wave * per, g1 = min(G, g0 + per);
    if (g0 >= g1) return;
    int cur_r = -1;
    short8 wf[4][2];
    const short8 z8 = {0, 0, 0, 0, 0, 0, 0, 0};
    // prefetched index state for group g
    int e = perm_type[(g0 << 4) + c];
    int hn = e >= 0 ? head[e] : 0;
    int tn = e >= 0 ? tail[e] : 0;
    int r = group_rel[g0];
    for (int g = g0; g < g1; ++g) {
        int e_c = e, hn_c = hn, tn_c = tn, r_c = r;
        if (g + 1 < g1) {                          // prefetch next group's indices
            e = perm_type[((g + 1) << 4) + c];
            hn = e >= 0 ? head[e] : 0;
            tn = e >= 0 ? tail[e] : 0;
            r = group_rel[g + 1];
        }
        if (r_c != cur_r) {                        // rare: W^T frag reload (L2)
            cur_r = r_c;
            const short* wp = wfrag + (size_t)r_c * 4096;
            for (int t4 = 0; t4 < 4; ++t4)
                for (int kh = 0; kh < 2; ++kh)
                    wf[t4][kh] = *(const short8*)(wp + ((t4 * 2 + kh) * 64 + lane) * 8);
        }
        // B-frag: head row (bf16, direct b128 loads, no convert)
        const unsigned short* hr = ego_bf + (size_t)hn_c * 64;
        short8 b0 = *(const short8*)(hr + q * 8);
        short8 b1 = *(const short8*)(hr + 32 + q * 8);
        if (e_c < 0) { b0 = z8; b1 = z8; }
        f32x4 acc[4];
        for (int t4 = 0; t4 < 4; ++t4) {
            f32x4 a = {0.f, 0.f, 0.f, 0.f};
            a = __builtin_amdgcn_mfma_f32_16x16x32_bf16(wf[t4][0], b0, a, 0, 0, 0);
            a = __builtin_amdgcn_mfma_f32_16x16x32_bf16(wf[t4][1], b1, a, 0, 0, 0);
            acc[t4] = a;
        }
        // tail dot: lane's own edge c; acc[t4][i] = outcol t4*16+q*4+i of edge c
        const unsigned short* tr = ego_bf + (size_t)tn_c * 64 + q * 4;
        float d = 0.f;
        for (int t4 = 0; t4 < 4; ++t4) {
            ushort4 tv = *(const ushort4*)(tr + t4 * 16);
            d += acc[t4][0] * bf2f(tv.x) + acc[t4][1] * bf2f(tv.y)
               + acc[t4][2] * bf2f(tv.z) + acc[t4][3] * bf2f(tv.w);
        }
        d += __shfl_xor(d, 16);
        d += __shfl_xor(d, 32);
        if (q == 0 && e_c >= 0) {
            float s = d > 0.f ? d : NEG_SLOPE * d;
            exp_s[e_c] = __expf(s);
        }
    }
}

// ---------------- K5: per-head aggregation, 4 edges x 16 lanes ----------------
__global__ void __launch_bounds__(256) k5_agg(
        const unsigned short* __restrict__ ego_bf, const int* __restrict__ tail,
        const int* __restrict__ perm_head, const int* __restrict__ head_off,
        const float* __restrict__ exp_s, float* __restrict__ out, int N) {
    int wave = (blockIdx.x * blockDim.x + threadIdx.x) >> 6;
    int lane = threadIdx.x & 63;
    if (wave >= N) return;
    int g = lane >> 4, c = lane & 15;          // g = edge slot, c -> cols 4c..4c+3
    int s0 = head_off[wave], s1 = head_off[wave + 1];
    int cnt = s1 - s0;
    float a0 = 0.f, a1 = 0.f, a2 = 0.f, a3 = 0.f, den = 0.f;
    for (int base = s0; base < s1; base += 64) {
        int idx = base + lane;
        int eL = perm_head[idx < s1 ? idx : s1 - 1];   // coalesced preload
        int tnL = tail[eL];
        float wL = exp_s[eL];
        int ng = min(64, s1 - base);
        for (int j0 = 0; j0 < ng; j0 += 4) {
            int j = j0 + g;                            // j <= 63 always
            int tn = __shfl(tnL, j);
            float we = __shfl(wL, j);
            if (j >= ng) we = 0.f;
            ushort4 tv = *(const ushort4*)(ego_bf + (size_t)tn * 64 + c * 4);
            a0 += we * bf2f(tv.x);
            a1 += we * bf2f(tv.y);
            a2 += we * bf2f(tv.z);
            a3 += we * bf2f(tv.w);
            den += we;
        }
    }
    den += __shfl_xor(den, 16); den += __shfl_xor(den, 32);
    a0 += __shfl_xor(a0, 16); a0 += __shfl_xor(a0, 32);
    a1 += __shfl_xor(a1, 16); a1 += __shfl_xor(a1, 32);
    a2 += __shfl_xor(a2, 16); a2 += __shfl_xor(a2, 32);
    a3 += __shfl_xor(a3, 16); a3 += __shfl_xor(a3, 32);
    float4 v;
    if (cnt > 0) {
        float sc = 1.f / (den * (float)cnt);
        v.x = a0 * sc; v.y = a1 * sc; v.z = a2 * sc; v.w = a3 * sc;
    } else {
        v.x = 0.f; v.y = 0.f; v.z = 0.f; v.w = 0.f;
    }
    if (lane < 16) *(float4*)(out + (size_t)wave * 64 + lane * 4) = v;
}

extern "C" void kernel_launch(void* const* d_in, const int* in_sizes, int n_in,
                              void* d_out, int out_size, void* d_ws, size_t ws_size,
                              hipStream_t stream) {
    const float* ego = (const float*)d_in[0];
    const float* rw  = (const float*)d_in[1];
    const int* eidx  = (const int*)d_in[2];
    const int* etyp  = (const int*)d_in[3];
    int N = in_sizes[0] / 64;
    int E = in_sizes[3];
    const int* head = eidx;
    const int* tail = eidx + E;
    float* out = (float*)d_out;

    // workspace layout (256B aligned sections), ~30 MB total
    char* ws = (char*)d_ws;
    size_t o = 0;
    auto take = [&](size_t bytes) -> char* {
        char* p = ws + o;
        o = (o + bytes + 255) & ~(size_t)255;
        return p;
    };
    int PT   = E + 256;
    int Gmax = (E + 15) / 16 + 16;
    int nb2  = (N + 511) / 512;
    unsigned short* ego_bf = (unsigned short*)take((size_t)N * 64 * 2);
    short* wfrag      = (short*)take(16 * 4096 * 2);   // 128 KB W^T frags
    float* exp_s      = (float*)take((size_t)E * 4);
    int* perm_type    = (int*)take((size_t)PT * 4);
    int* perm_head    = (int*)take((size_t)E * 4);
    int* head_cnt     = (int*)take((size_t)N * 4);
    int* head_off     = (int*)take((size_t)(N + 1) * 4);
    int* head_cur     = (int*)take((size_t)N * 4);
    int* type_cnt     = (int*)take(64);
    int* type_off_pad = (int*)take(68);
    int* type_fill    = (int*)take(64);
    int* group_rel    = (int*)take((size_t)Gmax * 4);
    int* partial      = (int*)take((size_t)nb2 * 4);
    int* blk_off      = (int*)take((size_t)nb2 * 4);
    (void)ws_size; (void)n_in; (void)out_size;

    int initN = (N > PT ? N : PT);
    k0_init<<<(initN + 255) / 256, 256, 0, stream>>>(head_cnt, head_cur, type_cnt,
                                                     perm_type, N, PT);
    int NE8 = N * 64 / 8;
    k_bf<<<(NE8 + 255) / 256, 256, 0, stream>>>(ego, ego_bf, NE8);
    k_w<<<16, 512, 0, stream>>>(rw, wfrag);

    int nchunks = (E + CHUNK - 1) / CHUNK;
    k1_hist<<<nchunks, 256, 0, stream>>>(head, etyp, E, head_cnt, type_cnt);
    k2a<<<nb2, 512, 0, stream>>>(head_cnt, N, partial);
    k2b<<<1, 64, 0, stream>>>(partial, nb2, blk_off, type_cnt, type_off_pad, type_fill);
    k2c<<<nb2, 512, 0, stream>>>(head_cnt, N, blk_off, head_off, E);
    k3_scatter<<<nchunks, 256, 0, stream>>>(head, etyp, E, head_off, head_cur,
                                            type_fill, perm_type, perm_head);
    k3b<<<(Gmax + 255) / 256, 256, 0, stream>>>(type_off_pad, group_rel, Gmax);

    int blocks4 = 4096;                    // 16384 waves, ~5 groups each
    int n_waves = blocks4 * (256 / 64);
    k4_scores<<<blocks4, 256, 0, stream>>>(ego_bf, wfrag, head, tail, perm_type,
                                           group_rel, type_off_pad, exp_s, n_waves);

    k5_agg<<<(N + 3) / 4, 256, 0, stream>>>(ego_bf, tail, perm_head, head_off,
                                            exp_s, out, N);
}

// Round 3
// 317.918 us; speedup vs baseline: 1.6892x; 1.1392x over previous
//
#include <hip/hip_runtime.h>
#include <stdint.h>

#define NEG_SLOPE 0.01f
#define CHUNK 4096

typedef float f32x4 __attribute__((ext_vector_type(4)));
typedef short short8 __attribute__((ext_vector_type(8)));

__device__ inline short f2bf(float f) {
    union { float f; uint32_t u; } x; x.f = f;
    uint32_t r = x.u + 0x7FFF + ((x.u >> 16) & 1);   // RNE
    return (short)(r >> 16);
}
__device__ inline float bf2f(unsigned short u) {
    union { uint32_t u; float f; } x; x.u = ((uint32_t)u) << 16; return x.f;
}

// ---------------- K0: init counters ----------------
__global__ void k0_init(int* head_cnt, int* head_cur, int* type_cnt, int N) {
    int i = blockIdx.x * blockDim.x + threadIdx.x;
    if (i < N) { head_cnt[i] = 0; head_cur[i] = 0; }
    if (i < 16) type_cnt[i] = 0;
}

// ---------------- K_bf: ego fp32 -> bf16 table ----------------
__global__ void __launch_bounds__(256) k_bf(const float* __restrict__ ego,
                                            unsigned short* __restrict__ ego_bf,
                                            int NE8) {
    int i = blockIdx.x * 256 + threadIdx.x;
    if (i >= NE8) return;
    const float4* p = (const float4*)ego + (size_t)i * 2;
    float4 a = p[0], b = p[1];
    short8 v;
    v[0] = f2bf(a.x); v[1] = f2bf(a.y); v[2] = f2bf(a.z); v[3] = f2bf(a.w);
    v[4] = f2bf(b.x); v[5] = f2bf(b.y); v[6] = f2bf(b.z); v[7] = f2bf(b.w);
    *(short8*)(ego_bf + (size_t)i * 8) = v;
}

// ---------------- K_w: pack W^T as MFMA A-fragments (bf16) ----------------
// A[m = t4*16 + (lane&15)][k = kh*32 + (lane>>4)*8 + j] = W[r][k][m]
__global__ void __launch_bounds__(512) k_w(const float* __restrict__ rw,
                                           short* __restrict__ wfrag) {
    int r = blockIdx.x;
    int tid = threadIdx.x;
    int lane = tid & 63, pair = tid >> 6;
    int t4 = pair >> 1, kh = pair & 1;
    int c = lane & 15, q = lane >> 4;
    int m = t4 * 16 + c;
    short8 f;
    for (int j = 0; j < 8; ++j) {
        int k = kh * 32 + q * 8 + j;
        f[j] = f2bf(rw[r * 4096 + k * 64 + m]);
    }
    *(short8*)(wfrag + ((size_t)((r * 4 + t4) * 2 + kh) * 64 + lane) * 8) = f;
}

// ---------------- K1: histograms ----------------
__global__ void __launch_bounds__(256) k1_hist(
        const int* __restrict__ head, const int* __restrict__ etype, int E,
        int* head_cnt, int* type_cnt) {
    __shared__ int lcnt[16];
    int t = threadIdx.x;
    if (t < 16) lcnt[t] = 0;
    __syncthreads();
    long long base = (long long)blockIdx.x * CHUNK;
    for (int i = t; i < CHUNK; i += 256) {
        long long e = base + i;
        if (e < E) {
            atomicAdd(&head_cnt[head[e]], 1);
            atomicAdd(&lcnt[etype[e]], 1);
        }
    }
    __syncthreads();
    if (t < 16 && lcnt[t]) atomicAdd(&type_cnt[t], lcnt[t]);
}

// ---------------- K2a: per-block partial sums of head_cnt ----------------
__global__ void __launch_bounds__(512) k2a(const int* __restrict__ head_cnt,
                                           int N, int* partial) {
    __shared__ int sw[8];
    int i = blockIdx.x * 512 + threadIdx.x;
    int v = (i < N) ? head_cnt[i] : 0;
    for (int off = 32; off; off >>= 1) v += __shfl_down(v, off);
    int w = threadIdx.x >> 6, lane = threadIdx.x & 63;
    if (lane == 0) sw[w] = v;
    __syncthreads();
    if (threadIdx.x == 0) {
        int s = 0;
        for (int j = 0; j < 8; ++j) s += sw[j];
        partial[blockIdx.x] = s;
    }
}

// ---------------- K2c: scan -> head_off (block prefix computed in-kernel) ----
__global__ void __launch_bounds__(512) k2c(const int* __restrict__ head_cnt,
                                           int N, const int* __restrict__ partial,
                                           int* head_off, int E) {
    __shared__ int s[512];
    __shared__ int bo_s;
    int t = threadIdx.x;
    if (t < 64) {
        int acc = 0;
        for (int i = t; i < blockIdx.x; i += 64) acc += partial[i];
        for (int off = 32; off; off >>= 1) acc += __shfl_down(acc, off);
        if (t == 0) bo_s = acc;
    }
    int i = blockIdx.x * 512 + t;
    int v = (i < N) ? head_cnt[i] : 0;
    s[t] = v;
    __syncthreads();
    for (int off = 1; off < 512; off <<= 1) {
        int x = (t >= off) ? s[t - off] : 0;
        __syncthreads();
        s[t] += x;
        __syncthreads();
    }
    if (i < N) head_off[i] = s[t] - v + bo_s;
    if (i == 0) head_off[N] = E;
}

// ---------------- K2t: type scan + pad-slot fill ----------------
__global__ void k2t(const int* __restrict__ type_cnt, int* type_off_pad,
                    int* type_fill, int* perm_type) {
    __shared__ int top[17], tcn[16];
    int lane = threadIdx.x;    // 64 threads
    if (lane < 16) {
        int tv = type_cnt[lane];
        int tp = (tv + 15) & ~15;
        int inc = tp;
        for (int off = 1; off < 16; off <<= 1) {
            int u = __shfl_up(inc, off);
            if (lane >= off) inc += u;
        }
        int excl = inc - tp;
        type_off_pad[lane] = excl;
        type_fill[lane] = excl;
        top[lane] = excl; tcn[lane] = tv;
        if (lane == 15) { type_off_pad[16] = inc; top[16] = inc; }
    }
    __syncthreads();
    for (int r = 0; r < 16; ++r) {
        int base = top[r] + tcn[r];
        int pads = top[r + 1] - base;
        if (lane < pads) perm_type[base + lane] = -1;
    }
}

// ---------------- K3: scatter into type buckets (LDS-aggregated) ----------
__global__ void __launch_bounds__(256) k3_scatter(
        const int* __restrict__ etype, int E, int* type_fill, int* perm_type) {
    __shared__ int lcnt[16], lbase[16], lcur[16];
    int t = threadIdx.x;
    if (t < 16) { lcnt[t] = 0; lcur[t] = 0; }
    __syncthreads();
    long long base = (long long)blockIdx.x * CHUNK;
    for (int i = t; i < CHUNK; i += 256) {
        long long e = base + i;
        if (e < E) atomicAdd(&lcnt[etype[e]], 1);
    }
    __syncthreads();
    if (t < 16) lbase[t] = atomicAdd(&type_fill[t], lcnt[t]);
    __syncthreads();
    for (int i = t; i < CHUNK; i += 256) {
        long long e = base + i;
        if (e < E) {
            int ty = etype[e];
            int rk = atomicAdd(&lcur[ty], 1);
            perm_type[lbase[ty] + rk] = (int)e;
        }
    }
}

// ---------------- K3b: per-group relation id ----------------
__global__ void k3b(const int* __restrict__ type_off_pad, int* group_rel, int Gmax) {
    int g = blockIdx.x * blockDim.x + threadIdx.x;
    if (g >= Gmax) return;
    int total = type_off_pad[16] >> 4;
    if (g >= total) return;
    int s = g << 4;
    int r = 0;
    while (r < 15 && s >= type_off_pad[r + 1]) ++r;
    group_rel[g] = r;
}

// ---------------- K4: scores via MFMA, pipelined gathers + fused CSR build --
// D = W^T(A-frag) x HeadRows(B-frag): D col (lane&15) = edge slot,
// D row (q*4+i, tiled by t4) = output column. Epilogue (q==0 lanes) builds
// the head-sorted (w, tail) arrays directly: one atomic + 2 stores per edge.
__global__ void __launch_bounds__(256) k4_scores(
        const unsigned short* __restrict__ ego_bf, const short* __restrict__ wfrag,
        const int* __restrict__ head, const int* __restrict__ tail,
        const int* __restrict__ perm_type, const int* __restrict__ group_rel,
        const int* __restrict__ type_off_pad, const int* __restrict__ head_off,
        int* __restrict__ head_cur, float* __restrict__ w_sorted,
        int* __restrict__ tail_sorted, int n_waves) {
    int wave = (blockIdx.x * blockDim.x + threadIdx.x) >> 6;
    int lane = threadIdx.x & 63;
    int c = lane & 15, q = lane >> 4;
    int G = type_off_pad[16] >> 4;
    int per = (G + n_waves - 1) / n_waves;
    int g0 = wave * per, g1 = min(G, g0 + per);
    if (g0 >= g1) return;
    const short8 z8 = {0, 0, 0, 0, 0, 0, 0, 0};

    // index pipeline, 2 deep (A = group g, B = group g+1)
    int eA = perm_type[(g0 << 4) + c];
    int hA = eA >= 0 ? head[eA] : 0;
    int tA = eA >= 0 ? tail[eA] : 0;
    int rA = group_rel[g0];
    int hoA = head_off[hA];
    int eB = -1, hB = 0, tB = 0, rB = rA, hoB = 0;
    if (g0 + 1 < g1) {
        eB = perm_type[((g0 + 1) << 4) + c];
        hB = eB >= 0 ? head[eB] : 0;
        tB = eB >= 0 ? tail[eB] : 0;
        rB = group_rel[g0 + 1];
        hoB = head_off[hB];
    }
    // row data for group g0
    const unsigned short* hr = ego_bf + (size_t)hA * 64;
    short8 b0c = *(const short8*)(hr + q * 8);
    short8 b1c = *(const short8*)(hr + 32 + q * 8);
    const unsigned short* tr = ego_bf + (size_t)tA * 64 + q * 4;
    ushort4 t0c = *(const ushort4*)(tr);
    ushort4 t1c = *(const ushort4*)(tr + 16);
    ushort4 t2c = *(const ushort4*)(tr + 32);
    ushort4 t3c = *(const ushort4*)(tr + 48);

    int cur_r = -1;
    short8 wf[4][2];
    for (int g = g0; g < g1; ++g) {
        // prefetch rows for g+1 (B indices already resident)
        const unsigned short* hrn = ego_bf + (size_t)hB * 64;
        short8 b0n = *(const short8*)(hrn + q * 8);
        short8 b1n = *(const short8*)(hrn + 32 + q * 8);
        const unsigned short* trn = ego_bf + (size_t)tB * 64 + q * 4;
        ushort4 t0n = *(const ushort4*)(trn);
        ushort4 t1n = *(const ushort4*)(trn + 16);
        ushort4 t2n = *(const ushort4*)(trn + 32);
        ushort4 t3n = *(const ushort4*)(trn + 48);
        // prefetch indices for g+2
        int eN = -1, hN = 0, tN = 0, rN = rB, hoN = 0;
        if (g + 2 < g1) {
            eN = perm_type[((g + 2) << 4) + c];
            hN = eN >= 0 ? head[eN] : 0;
            tN = eN >= 0 ? tail[eN] : 0;
            rN = group_rel[g + 2];
            hoN = head_off[hN];
        }
        if (rA != cur_r) {                       // wave-uniform, rare
            cur_r = rA;
            const short* wp = wfrag + (size_t)rA * 4096;
            for (int t4 = 0; t4 < 4; ++t4)
                for (int kh = 0; kh < 2; ++kh)
                    wf[t4][kh] = *(const short8*)(wp + ((t4 * 2 + kh) * 64 + lane) * 8);
        }
        short8 bb0 = b0c, bb1 = b1c;
        if (eA < 0) { bb0 = z8; bb1 = z8; }
        f32x4 acc[4];
        for (int t4 = 0; t4 < 4; ++t4) {
            f32x4 a = {0.f, 0.f, 0.f, 0.f};
            a = __builtin_amdgcn_mfma_f32_16x16x32_bf16(wf[t4][0], bb0, a, 0, 0, 0);
            a = __builtin_amdgcn_mfma_f32_16x16x32_bf16(wf[t4][1], bb1, a, 0, 0, 0);
            acc[t4] = a;
        }
        float d = acc[0][0] * bf2f(t0c.x) + acc[0][1] * bf2f(t0c.y)
                + acc[0][2] * bf2f(t0c.z) + acc[0][3] * bf2f(t0c.w)
                + acc[1][0] * bf2f(t1c.x) + acc[1][1] * bf2f(t1c.y)
                + acc[1][2] * bf2f(t1c.z) + acc[1][3] * bf2f(t1c.w)
                + acc[2][0] * bf2f(t2c.x) + acc[2][1] * bf2f(t2c.y)
                + acc[2][2] * bf2f(t2c.z) + acc[2][3] * bf2f(t2c.w)
                + acc[3][0] * bf2f(t3c.x) + acc[3][1] * bf2f(t3c.y)
                + acc[3][2] * bf2f(t3c.z) + acc[3][3] * bf2f(t3c.w);
        d += __shfl_xor(d, 16);
        d += __shfl_xor(d, 32);
        if (q == 0 && eA >= 0) {
            int p2 = hoA + atomicAdd(&head_cur[hA], 1);
            float s = d > 0.f ? d : NEG_SLOPE * d;
            w_sorted[p2] = __expf(s);
            tail_sorted[p2] = tA;
        }
        // rotate pipeline
        eA = eB; hA = hB; tA = tB; rA = rB; hoA = hoB;
        eB = eN; hB = hN; tB = tN; rB = rN; hoB = hoN;
        b0c = b0n; b1c = b1n;
        t0c = t0n; t1c = t1n; t2c = t2n; t3c = t3n;
    }
}

// ---------------- K5: per-head aggregation, streaming, 8 edges x 8 lanes ----
__global__ void __launch_bounds__(256) k5_agg(
        const unsigned short* __restrict__ ego_bf,
        const int* __restrict__ tail_sorted, const float* __restrict__ w_sorted,
        const int* __restrict__ head_off, float* __restrict__ out, int N) {
    int wave = (blockIdx.x * blockDim.x + threadIdx.x) >> 6;
    int lane = threadIdx.x & 63;
    if (wave >= N) return;
    int g8 = lane >> 3, c8 = lane & 7;   // g8 = edge slot, c8 -> cols 8c8..8c8+7
    int s0 = head_off[wave], s1 = head_off[wave + 1];
    int cnt = s1 - s0;
    float a0 = 0.f, a1 = 0.f, a2 = 0.f, a3 = 0.f;
    float a4 = 0.f, a5 = 0.f, a6 = 0.f, a7 = 0.f, den = 0.f;
    for (int base = s0; base < s1; base += 64) {
        int idx = base + lane;
        int tnL = 0; float wL = 0.f;
        if (idx < s1) { tnL = tail_sorted[idx]; wL = w_sorted[idx]; }   // coalesced
        int ng = min(64, s1 - base);
        for (int j0 = 0; j0 < ng; j0 += 8) {
            int j = j0 + g8;
            int tn = __shfl(tnL, j);
            float we = __shfl(wL, j);
            if (j >= ng) we = 0.f;
            short8 tv = *(const short8*)(ego_bf + (size_t)tn * 64 + c8 * 8);
            a0 += we * bf2f((unsigned short)tv[0]);
            a1 += we * bf2f((unsigned short)tv[1]);
            a2 += we * bf2f((unsigned short)tv[2]);
            a3 += we * bf2f((unsigned short)tv[3]);
            a4 += we * bf2f((unsigned short)tv[4]);
            a5 += we * bf2f((unsigned short)tv[5]);
            a6 += we * bf2f((unsigned short)tv[6]);
            a7 += we * bf2f((unsigned short)tv[7]);
            den += we;
        }
    }
    for (int off = 8; off < 64; off <<= 1) {      // sum over g8, keep c8
        den += __shfl_xor(den, off);
        a0 += __shfl_xor(a0, off); a1 += __shfl_xor(a1, off);
        a2 += __shfl_xor(a2, off); a3 += __shfl_xor(a3, off);
        a4 += __shfl_xor(a4, off); a5 += __shfl_xor(a5, off);
        a6 += __shfl_xor(a6, off); a7 += __shfl_xor(a7, off);
    }
    if (lane < 8) {
        float sc = (cnt > 0) ? 1.f / (den * (float)cnt) : 0.f;
        float4 v0 = {a0 * sc, a1 * sc, a2 * sc, a3 * sc};
        float4 v1 = {a4 * sc, a5 * sc, a6 * sc, a7 * sc};
        float* op = out + (size_t)wave * 64 + c8 * 8;
        *(float4*)op = v0;
        *(float4*)(op + 4) = v1;
    }
}

extern "C" void kernel_launch(void* const* d_in, const int* in_sizes, int n_in,
                              void* d_out, int out_size, void* d_ws, size_t ws_size,
                              hipStream_t stream) {
    const float* ego = (const float*)d_in[0];
    const float* rw  = (const float*)d_in[1];
    const int* eidx  = (const int*)d_in[2];
    const int* etyp  = (const int*)d_in[3];
    int N = in_sizes[0] / 64;
    int E = in_sizes[3];
    const int* head = eidx;
    const int* tail = eidx + E;
    float* out = (float*)d_out;

    char* ws = (char*)d_ws;
    size_t o = 0;
    auto take = [&](size_t bytes) -> char* {
        char* p = ws + o;
        o = (o + bytes + 255) & ~(size_t)255;
        return p;
    };
    int PT   = E + 256;
    int Gmax = (E + 15) / 16 + 16;
    int nb2  = (N + 511) / 512;
    unsigned short* ego_bf = (unsigned short*)take((size_t)N * 64 * 2);
    short* wfrag      = (short*)take(16 * 4096 * 2);
    float* w_sorted   = (float*)take((size_t)E * 4);
    int* tail_sorted  = (int*)take((size_t)E * 4);
    int* perm_type    = (int*)take((size_t)PT * 4);
    int* head_cnt     = (int*)take((size_t)N * 4);
    int* head_off     = (int*)take((size_t)(N + 1) * 4);
    int* head_cur     = (int*)take((size_t)N * 4);
    int* type_cnt     = (int*)take(64);
    int* type_off_pad = (int*)take(68);
    int* type_fill    = (int*)take(64);
    int* group_rel    = (int*)take((size_t)Gmax * 4);
    int* partial      = (int*)take((size_t)nb2 * 4);
    (void)ws_size; (void)n_in; (void)out_size;

    k0_init<<<(N + 255) / 256, 256, 0, stream>>>(head_cnt, head_cur, type_cnt, N);
    int NE8 = N * 64 / 8;
    k_bf<<<(NE8 + 255) / 256, 256, 0, stream>>>(ego, ego_bf, NE8);
    k_w<<<16, 512, 0, stream>>>(rw, wfrag);

    int nchunks = (E + CHUNK - 1) / CHUNK;
    k1_hist<<<nchunks, 256, 0, stream>>>(head, etyp, E, head_cnt, type_cnt);
    k2a<<<nb2, 512, 0, stream>>>(head_cnt, N, partial);
    k2c<<<nb2, 512, 0, stream>>>(head_cnt, N, partial, head_off, E);
    k2t<<<1, 64, 0, stream>>>(type_cnt, type_off_pad, type_fill, perm_type);
    k3_scatter<<<nchunks, 256, 0, stream>>>(etyp, E, type_fill, perm_type);
    k3b<<<(Gmax + 255) / 256, 256, 0, stream>>>(type_off_pad, group_rel, Gmax);

    int blocks4 = 2048;                    // 8192 waves, ~9.5 groups each
    int n_waves = blocks4 * (256 / 64);
    k4_scores<<<blocks4, 256, 0, stream>>>(ego_bf, wfrag, head, tail, perm_type,
                                           group_rel, type_off_pad, head_off,
                                           head_cur, w_sorted, tail_sorted, n_waves);

    k5_agg<<<(N + 3) / 4, 256, 0, stream>>>(ego_bf, tail_sorted, w_sorted,
                                            head_off, out, N);
}